// Round 1
// baseline (4242.006 us; speedup 1.0000x reference)
//
#include <hip/hip_runtime.h>
#include <stdint.h>
#include <stddef.h>

#define T_SEQ 512
#define HDIM 512
#define CTXN 10
#define OUT_T (T_SEQ - 2 * CTXN)   // 492
#define GM 16
#define GC 16

typedef __bf16 bf16x8 __attribute__((ext_vector_type(8)));
typedef float f32x4 __attribute__((ext_vector_type(4)));
typedef unsigned short u16x4 __attribute__((ext_vector_type(4)));
typedef unsigned short u16x8 __attribute__((ext_vector_type(8)));
typedef unsigned long long u64;

__device__ __forceinline__ unsigned short f2bf(float f) {
  union { float f; unsigned u; } v; v.f = f;
  unsigned r = v.u + 0x7FFFu + ((v.u >> 16) & 1u);  // RNE
  return (unsigned short)(r >> 16);
}
__device__ __forceinline__ float bf2f(unsigned short b) {
  union { unsigned u; float f; } v; v.u = ((unsigned)b) << 16;
  return v.f;
}

// ------------- split fp32 weights into (hi, lo) bf16 pairs -------------
__global__ void split_w(const float* __restrict__ wih_f, const float* __restrict__ wih_b,
                        const float* __restrict__ whh_f, const float* __restrict__ whh_b,
                        unsigned short* __restrict__ wih_hi, unsigned short* __restrict__ wih_lo,
                        unsigned short* __restrict__ whh_hi, unsigned short* __restrict__ whh_lo) {
  const int which = blockIdx.y;
  const float* src = which == 0 ? wih_f : which == 1 ? wih_b : which == 2 ? whh_f : whh_b;
  const size_t off = (which & 1) ? (size_t)1536 * HDIM : 0;
  unsigned short* dhi = (which < 2 ? wih_hi : whh_hi) + off;
  unsigned short* dlo = (which < 2 ? wih_lo : whh_lo) + off;
  size_t i = ((size_t)blockIdx.x * 256 + threadIdx.x) * 4;
  float4 v = *(const float4*)(src + i);
  u16x4 h, l;
  h.x = f2bf(v.x); l.x = f2bf(v.x - bf2f(h.x));
  h.y = f2bf(v.y); l.y = f2bf(v.y - bf2f(h.y));
  h.z = f2bf(v.z); l.z = f2bf(v.z - bf2f(h.z));
  h.w = f2bf(v.w); l.w = f2bf(v.w - bf2f(h.w));
  *(u16x4*)(dhi + i) = h;
  *(u16x4*)(dlo + i) = l;
}

// ------------- fused split-precision bidirectional GRU recurrence -------------
// 8 groups = (4 batch chunks of 16) x (2 dirs); 32 blocks/group.
// Sync redesign: h is exchanged as tagged 64-bit words {tag=step | (hi16|lo16)}
// in a depth-2 ring. The 8B store IS the flag (single-copy atomic), so
// store->poll is ONE LLC traversal: no vmcnt(0) drain, no counter RMW, no
// separate data read. gh waves poll exactly the words they feed to MFMA and
// unpack in registers (no Hh/Hl LDS). gi waves load x fragments directly from
// L2 and compute during the poll. 2 barriers/step (was 4).
//
// Depth-2 safety: a block writes h(t+1) only after seeing all tags==t, which
// implies every block stored h(t) and therefore retired its h(t-1) reads
// (barrier orders reads before stores within each block). Writer slot
// (t+1)&1 != reader slot t&1, and a polling reader can only ever observe
// tags {t-2, t} in its slot, so ==-polling terminates.
__global__ __launch_bounds__(512)
void gru_rec(const float* __restrict__ x,
             const unsigned short* __restrict__ wih_hi, const unsigned short* __restrict__ wih_lo,
             const unsigned short* __restrict__ whh_hi, const unsigned short* __restrict__ whh_lo,
             const float* __restrict__ bih_f, const float* __restrict__ bhh_f,
             const float* __restrict__ bih_b, const float* __restrict__ bhh_b,
             float* __restrict__ out, u64* hbuf) {
  const int bx = blockIdx.x;
  const int g  = bx & 7;                 // group; %8 biases same-XCD placement
  const int nb = bx >> 3;                // 0..31 -> col slice
  const int d  = g & 1;
  const int b0 = (g >> 1) * GM;
  const int tid = threadIdx.x;
  const int lane = tid & 63;
  const int wave = tid >> 6;             // 0..7
  const int lr = lane & 15, lq = lane >> 4;
  const int m = wave & 1;                // 0: ih (gi), 1: hh (gh)
  const int q = wave >> 1;               // K-quarter

  __shared__ float part[2][4][3][16][17];    // [matrix][quarter][gate][col][batch]
  __shared__ float hloc[GM][GC];             // fp32 local h slice (exact)
  __shared__ float bi_s[3][GC], bh_s[3][GC];

  if (tid < 256) hloc[tid >> 4][tid & 15] = 0.f;
  if (tid < 48) {
    int g3 = tid >> 4, j = tid & 15;
    int row = g3 * HDIM + nb * GC + j;
    bi_s[g3][j] = (d ? bih_b : bih_f)[row];
    bh_s[g3][j] = (d ? bhh_b : bhh_f)[row];
  }

  // preload weight fragments (loop-invariant): 24 frags = 96 VGPRs
  const size_t wd = (size_t)d * 1536 * HDIM;
  const unsigned short* Whi = (m ? whh_hi : wih_hi) + wd;
  const unsigned short* Wlo = (m ? whh_lo : wih_lo) + wd;
  bf16x8 wh[3][4], wl[3][4];
#pragma unroll
  for (int g3 = 0; g3 < 3; g3++)
#pragma unroll
    for (int kc = 0; kc < 4; kc++) {
      size_t ofs = (size_t)(g3 * HDIM + nb * GC + lr) * HDIM + q * 128 + kc * 32 + lq * 8;
      wh[g3][kc] = *(const bf16x8*)(Whi + ofs);
      wl[g3][kc] = *(const bf16x8*)(Wlo + ofs);
    }

  u64* hb = hbuf + (size_t)g * 2 * GM * HDIM;   // [2 slots][16][512] u64 tagged words
  const int rbase = lr * HDIM + q * 128 + lq * 8;

  for (int s = 0; s < T_SEQ; s++) {
    const int t = d ? (T_SEQ - 1 - s) : s;
    f32x4 acc[3];
    acc[0] = f32x4{0.f, 0.f, 0.f, 0.f};
    acc[1] = f32x4{0.f, 0.f, 0.f, 0.f};
    acc[2] = f32x4{0.f, 0.f, 0.f, 0.f};

    if (m == 0) {
      // ---- gi: x fragments straight from global (L2-shared within group)
      const float* xrow = x + ((size_t)(b0 + lr) * T_SEQ + t) * HDIM + q * 128 + lq * 8;
      float4 xa[4], xb[4];
#pragma unroll
      for (int kc = 0; kc < 4; kc++) {
        xa[kc] = *(const float4*)(xrow + kc * 32);
        xb[kc] = *(const float4*)(xrow + kc * 32 + 4);
      }
#pragma unroll
      for (int kc = 0; kc < 4; kc++) {
        float xe[8] = {xa[kc].x, xa[kc].y, xa[kc].z, xa[kc].w,
                       xb[kc].x, xb[kc].y, xb[kc].z, xb[kc].w};
        union { u16x8 u; bf16x8 b; } Ah, Al;
#pragma unroll
        for (int i = 0; i < 8; i++) {
          unsigned short hh = f2bf(xe[i]);
          Ah.u[i] = hh;
          Al.u[i] = f2bf(xe[i] - bf2f(hh));
        }
#pragma unroll
        for (int g3 = 0; g3 < 3; g3++) {
          acc[g3] = __builtin_amdgcn_mfma_f32_16x16x32_bf16(Ah.b, wh[g3][kc], acc[g3], 0, 0, 0);
          acc[g3] = __builtin_amdgcn_mfma_f32_16x16x32_bf16(Al.b, wh[g3][kc], acc[g3], 0, 0, 0);
          acc[g3] = __builtin_amdgcn_mfma_f32_16x16x32_bf16(Ah.b, wl[g3][kc], acc[g3], 0, 0, 0);
        }
      }
    } else {
      // ---- gh: poll tagged words for exactly the fragment this lane consumes
      const u64* rp = hb + (size_t)(s & 1) * GM * HDIM + rbase;
      const unsigned want = (unsigned)s;
      u64 cur[8], nxt[8];
#pragma unroll
      for (int i = 0; i < 8; i++)
        cur[i] = __hip_atomic_load(rp + i, __ATOMIC_RELAXED, __HIP_MEMORY_SCOPE_AGENT);
#pragma unroll
      for (int kc = 0; kc < 4; kc++) {
        if (kc < 3) {  // issue next chunk before polling current (overlap)
#pragma unroll
          for (int i = 0; i < 8; i++)
            nxt[i] = __hip_atomic_load(rp + (kc + 1) * 32 + i,
                                       __ATOMIC_RELAXED, __HIP_MEMORY_SCOPE_AGENT);
        }
        int it = 0;
        while (true) {
          bool ok = true;
#pragma unroll
          for (int i = 0; i < 8; i++) ok &= ((unsigned)(cur[i] >> 32) == want);
          if (ok || ++it > (1 << 20)) break;   // cap: wrong-but-terminating
#pragma unroll
          for (int i = 0; i < 8; i++)
            cur[i] = __hip_atomic_load(rp + kc * 32 + i,
                                       __ATOMIC_RELAXED, __HIP_MEMORY_SCOPE_AGENT);
        }
        union { u16x8 u; bf16x8 b; } Ah, Al;
#pragma unroll
        for (int i = 0; i < 8; i++) {
          unsigned dd = (unsigned)cur[i];
          Ah.u[i] = (unsigned short)(dd >> 16);
          Al.u[i] = (unsigned short)(dd & 0xffffu);
        }
#pragma unroll
        for (int g3 = 0; g3 < 3; g3++) {
          acc[g3] = __builtin_amdgcn_mfma_f32_16x16x32_bf16(Ah.b, wh[g3][kc], acc[g3], 0, 0, 0);
          acc[g3] = __builtin_amdgcn_mfma_f32_16x16x32_bf16(Al.b, wh[g3][kc], acc[g3], 0, 0, 0);
          acc[g3] = __builtin_amdgcn_mfma_f32_16x16x32_bf16(Ah.b, wl[g3][kc], acc[g3], 0, 0, 0);
        }
        if (kc < 3) {
#pragma unroll
          for (int i = 0; i < 8; i++) cur[i] = nxt[i];
        }
      }
    }

    // C layout: reg r at (lr,lq) holds D[row=lq*4+r=batch][col=lr]
#pragma unroll
    for (int g3 = 0; g3 < 3; g3++)
#pragma unroll
      for (int r = 0; r < 4; r++)
        part[m][q][g3][lr][lq * 4 + r] = acc[g3][r];
    __syncthreads();

    // ---- gates: 256 threads, one (batch b, col j) each
    if (tid < 256) {
      const int b = tid >> 4, j = tid & 15;
      const int col = nb * GC + j;
      float xv = x[((size_t)(b0 + b) * T_SEQ + t) * HDIM + col];   // L1/L2-hot
      float ir = 0.f, iz = 0.f, inn = 0.f, hr = 0.f, hz = 0.f, hnn = 0.f;
#pragma unroll
      for (int qq = 0; qq < 4; qq++) {
        ir  += part[0][qq][0][j][b];
        iz  += part[0][qq][1][j][b];
        inn += part[0][qq][2][j][b];
        hr  += part[1][qq][0][j][b];
        hz  += part[1][qq][1][j][b];
        hnn += part[1][qq][2][j][b];
      }
      float rr = 1.f / (1.f + expf(-(ir + bi_s[0][j] + hr + bh_s[0][j])));
      float zz = 1.f / (1.f + expf(-(iz + bi_s[1][j] + hz + bh_s[1][j])));
      float nn = tanhf(inn + bi_s[2][j] + rr * (hnn + bh_s[2][j]));
      float hv = (1.f - zz) * nn + zz * hloc[b][j];
      hloc[b][j] = hv;
      unsigned short h16 = f2bf(hv);
      unsigned short l16 = f2bf(hv - bf2f(h16));
      // tagged store: data + readiness in one atomic 8B word, fire-and-forget
      u64* wr = hb + (size_t)((s + 1) & 1) * GM * HDIM;
      u64 wv = ((u64)(unsigned)(s + 1) << 32) |
               (u64)(((unsigned)h16 << 16) | (unsigned)l16);
      __hip_atomic_store(&wr[b * HDIM + col], wv,
                         __ATOMIC_RELAXED, __HIP_MEMORY_SCOPE_AGENT);
      if (s >= CTXN && s < T_SEQ - CTXN)
        out[((size_t)(b0 + b) * OUT_T + (s - CTXN)) * 1024 + d * HDIM + col] = hv + xv;
    }
    __syncthreads();   // protect part[] / hloc for next step
  }
}

extern "C" void kernel_launch(void* const* d_in, const int* in_sizes, int n_in,
                              void* d_out, int out_size, void* d_ws, size_t ws_size,
                              hipStream_t stream) {
  (void)in_sizes; (void)n_in; (void)out_size; (void)ws_size;
  const float* v_in  = (const float*)d_in[0];
  const float* Wih_f = (const float*)d_in[1];
  const float* Whh_f = (const float*)d_in[2];
  const float* bih_f = (const float*)d_in[3];
  const float* bhh_f = (const float*)d_in[4];
  const float* Wih_b = (const float*)d_in[5];
  const float* Whh_b = (const float*)d_in[6];
  const float* bih_b = (const float*)d_in[7];
  const float* bhh_b = (const float*)d_in[8];
  float* out = (float*)d_out;
  char* ws = (char*)d_ws;

  // ws layout (~13 MB total):
  //   [0, 1M)         hbuf : 8 groups x 2 slots x 16 x 512 u64 tagged words
  //   [1M,  +3M)      wih_hi [2][1536][512] bf16
  //   [4M,  +3M)      wih_lo
  //   [7M,  +3M)      whh_hi
  //   [10M, +3M)      whh_lo
  u64* hbuf = (u64*)ws;
  unsigned short* wih_hi = (unsigned short*)(ws + (size_t)(1 << 20));
  unsigned short* wih_lo = (unsigned short*)(ws + (size_t)(4 << 20));
  unsigned short* whh_hi = (unsigned short*)(ws + (size_t)(7 << 20));
  unsigned short* whh_lo = (unsigned short*)(ws + (size_t)(10 << 20));

  // zero hbuf: slot0 tag=0 data=0 == valid h(0)=0; slot1 tag 0 != 1 -> polled
  hipMemsetAsync(ws, 0, (size_t)8 * 2 * GM * HDIM * 8, stream);
  split_w<<<dim3(768, 4), 256, 0, stream>>>(Wih_f, Wih_b, Whh_f, Whh_b,
                                            wih_hi, wih_lo, whh_hi, whh_lo);
  gru_rec<<<256, 512, 0, stream>>>(v_in, wih_hi, wih_lo, whh_hi, whh_lo,
                                   bih_f, bhh_f, bih_b, bhh_b, out, hbuf);
}

// Round 2
// 2112.519 us; speedup vs baseline: 2.0080x; 2.0080x over previous
//
#include <hip/hip_runtime.h>
#include <stdint.h>
#include <stddef.h>

#define T_SEQ 512
#define HDIM 512
#define CTXN 10
#define OUT_T (T_SEQ - 2 * CTXN)   // 492
#define GM 16
#define GC 16
#define NSLOT 8192                 // GM*HDIM u64 words per ring slot

typedef __bf16 bf16x8 __attribute__((ext_vector_type(8)));
typedef float f32x4 __attribute__((ext_vector_type(4)));
typedef unsigned short u16x4 __attribute__((ext_vector_type(4)));
typedef unsigned short u16x8 __attribute__((ext_vector_type(8)));
typedef unsigned long long u64;

__device__ __forceinline__ unsigned short f2bf(float f) {
  union { float f; unsigned u; } v; v.f = f;
  unsigned r = v.u + 0x7FFFu + ((v.u >> 16) & 1u);  // RNE
  return (unsigned short)(r >> 16);
}
__device__ __forceinline__ float bf2f(unsigned short b) {
  union { unsigned u; float f; } v; v.u = ((unsigned)b) << 16;
  return v.f;
}

// ------------- split fp32 weights into (hi, lo) bf16 pairs -------------
__global__ void split_w(const float* __restrict__ wih_f, const float* __restrict__ wih_b,
                        const float* __restrict__ whh_f, const float* __restrict__ whh_b,
                        unsigned short* __restrict__ wih_hi, unsigned short* __restrict__ wih_lo,
                        unsigned short* __restrict__ whh_hi, unsigned short* __restrict__ whh_lo) {
  const int which = blockIdx.y;
  const float* src = which == 0 ? wih_f : which == 1 ? wih_b : which == 2 ? whh_f : whh_b;
  const size_t off = (which & 1) ? (size_t)1536 * HDIM : 0;
  unsigned short* dhi = (which < 2 ? wih_hi : whh_hi) + off;
  unsigned short* dlo = (which < 2 ? wih_lo : whh_lo) + off;
  size_t i = ((size_t)blockIdx.x * 256 + threadIdx.x) * 4;
  float4 v = *(const float4*)(src + i);
  u16x4 h, l;
  h.x = f2bf(v.x); l.x = f2bf(v.x - bf2f(h.x));
  h.y = f2bf(v.y); l.y = f2bf(v.y - bf2f(h.y));
  h.z = f2bf(v.z); l.z = f2bf(v.z - bf2f(h.z));
  h.w = f2bf(v.w); l.w = f2bf(v.w - bf2f(h.w));
  *(u16x4*)(dhi + i) = h;
  *(u16x4*)(dlo + i) = l;
}

// ------------- fused split-precision bidirectional GRU recurrence -------------
// 8 groups = (4 batch chunks of 16) x (2 dirs); 32 blocks/group.
// h exchange: tagged 64-bit words {tag=step | (hi16|lo16)} in a depth-2 ring,
// stored in MFMA-FRAGMENT-MAJOR wire layout:
//   W(c,b) = (c>>7)*2048 + ((((c>>5)&3)*8 + (c&7)))*64 + ((c>>3)&3)*16 + b
// so a gh wave's load for fixed (kc,i) is 64 consecutive u64 = 512B coalesced,
// and the writer's 64 stores per wave form 2x256B contiguous chunks.
// The 8B store IS the flag (single-copy atomic): store->poll is ONE LLC
// traversal. s_sleep backoff bounds poll traffic. 2 barriers/step.
//
// Depth-2 safety: a block stores h(s+1) only after all its gh waves observed
// every tag==s (the 4 waves collectively check all 8192 words), which implies
// every block finished reading slot (s-1)&1 == (s+1)&1. ==-poll terminates
// since a slot can only hold tags {s-2, s} while being polled for s.
__global__ __launch_bounds__(512)
void gru_rec(const float* __restrict__ x,
             const unsigned short* __restrict__ wih_hi, const unsigned short* __restrict__ wih_lo,
             const unsigned short* __restrict__ whh_hi, const unsigned short* __restrict__ whh_lo,
             const float* __restrict__ bih_f, const float* __restrict__ bhh_f,
             const float* __restrict__ bih_b, const float* __restrict__ bhh_b,
             float* __restrict__ out, u64* hbuf) {
  const int bx = blockIdx.x;
  const int g  = bx & 7;                 // group; %8 biases same-XCD placement
  const int nb = bx >> 3;                // 0..31 -> col slice
  const int d  = g & 1;
  const int b0 = (g >> 1) * GM;
  const int tid = threadIdx.x;
  const int lane = tid & 63;
  const int wave = tid >> 6;             // 0..7
  const int lr = lane & 15, lq = lane >> 4;
  const int m = wave & 1;                // 0: ih (gi), 1: hh (gh)
  const int q = wave >> 1;               // K-quarter

  __shared__ float part[2][4][3][16][17];    // [matrix][quarter][gate][col][batch]
  __shared__ float hloc[GM][GC + 1];         // fp32 local h slice (exact), padded
  __shared__ float bi_s[3][GC], bh_s[3][GC];

  if (tid < 256) hloc[tid >> 4][tid & 15] = 0.f;
  if (tid < 48) {
    int g3 = tid >> 4, j = tid & 15;
    int row = g3 * HDIM + nb * GC + j;
    bi_s[g3][j] = (d ? bih_b : bih_f)[row];
    bh_s[g3][j] = (d ? bhh_b : bhh_f)[row];
  }

  // preload weight fragments (loop-invariant): 24 frags = 96 regs (AGPR-able)
  const size_t wd = (size_t)d * 1536 * HDIM;
  const unsigned short* Whi = (m ? whh_hi : wih_hi) + wd;
  const unsigned short* Wlo = (m ? whh_lo : wih_lo) + wd;
  bf16x8 wh[3][4], wl[3][4];
#pragma unroll
  for (int g3 = 0; g3 < 3; g3++)
#pragma unroll
    for (int kc = 0; kc < 4; kc++) {
      size_t ofs = (size_t)(g3 * HDIM + nb * GC + lr) * HDIM + q * 128 + kc * 32 + lq * 8;
      wh[g3][kc] = *(const bf16x8*)(Whi + ofs);
      wl[g3][kc] = *(const bf16x8*)(Wlo + ofs);
    }

  u64* hb = hbuf + (size_t)g * 2 * NSLOT;   // [2 slots][8192] tagged u64, wire layout

  // gate-thread geometry (remapped so h wire-stores coalesce):
  //   b = tid&15, j = ((tid>>4)&1)*8 + (tid>>5)
  const int gb  = tid & 15;
  const int gjj = (tid >> 4) & 1;
  const int gii = (tid >> 5) & 7;
  const int gj  = gjj * 8 + gii;
  const int gw  = (nb >> 3) * 2048 + (((nb >> 1) & 3) * 8 + gii) * 64 +
                  ((nb & 1) * 2 + gjj) * 16 + gb;

  for (int s = 0; s < T_SEQ; s++) {
    const int t = d ? (T_SEQ - 1 - s) : s;
    f32x4 acc[3];
    acc[0] = f32x4{0.f, 0.f, 0.f, 0.f};
    acc[1] = f32x4{0.f, 0.f, 0.f, 0.f};
    acc[2] = f32x4{0.f, 0.f, 0.f, 0.f};

    if (m == 0) {
      // ---- gi: x fragments from global (16 lines/instr, LLC-resident; overlaps gh poll)
      const float* xrow = x + ((size_t)(b0 + lr) * T_SEQ + t) * HDIM + q * 128 + lq * 8;
      float4 xa[4], xb[4];
#pragma unroll
      for (int kc = 0; kc < 4; kc++) {
        xa[kc] = *(const float4*)(xrow + kc * 32);
        xb[kc] = *(const float4*)(xrow + kc * 32 + 4);
      }
#pragma unroll
      for (int kc = 0; kc < 4; kc++) {
        float xe[8] = {xa[kc].x, xa[kc].y, xa[kc].z, xa[kc].w,
                       xb[kc].x, xb[kc].y, xb[kc].z, xb[kc].w};
        union { u16x8 u; bf16x8 b; } Ah, Al;
#pragma unroll
        for (int i = 0; i < 8; i++) {
          unsigned short hh = f2bf(xe[i]);
          Ah.u[i] = hh;
          Al.u[i] = f2bf(xe[i] - bf2f(hh));
        }
#pragma unroll
        for (int g3 = 0; g3 < 3; g3++) {
          acc[g3] = __builtin_amdgcn_mfma_f32_16x16x32_bf16(Ah.b, wh[g3][kc], acc[g3], 0, 0, 0);
          acc[g3] = __builtin_amdgcn_mfma_f32_16x16x32_bf16(Al.b, wh[g3][kc], acc[g3], 0, 0, 0);
          acc[g3] = __builtin_amdgcn_mfma_f32_16x16x32_bf16(Ah.b, wl[g3][kc], acc[g3], 0, 0, 0);
        }
      }
    } else {
      // ---- gh: coalesced tagged fragment loads straight into MFMA registers
      const u64* rp = hb + (size_t)(s & 1) * NSLOT + q * 2048 + lane;
      const unsigned want = (unsigned)s;
      u64 cur[4][8];
#pragma unroll
      for (int kc = 0; kc < 4; kc++)      // fire all 32 coalesced loads (MLP)
#pragma unroll
        for (int i = 0; i < 8; i++)
          cur[kc][i] = __hip_atomic_load(rp + (kc * 8 + i) * 64,
                                         __ATOMIC_RELAXED, __HIP_MEMORY_SCOPE_AGENT);
#pragma unroll
      for (int kc = 0; kc < 4; kc++) {
        int it = 0;
        while (true) {
          bool ok = true;
#pragma unroll
          for (int i = 0; i < 8; i++) ok &= ((unsigned)(cur[kc][i] >> 32) == want);
          if (ok || ++it > (1 << 18)) break;   // cap: wrong-but-terminating
          __builtin_amdgcn_s_sleep(1);         // bound poll traffic
#pragma unroll
          for (int i = 0; i < 8; i++)
            cur[kc][i] = __hip_atomic_load(rp + (kc * 8 + i) * 64,
                                           __ATOMIC_RELAXED, __HIP_MEMORY_SCOPE_AGENT);
        }
        union { u16x8 u; bf16x8 b; } Ah, Al;
#pragma unroll
        for (int i = 0; i < 8; i++) {
          unsigned dd = (unsigned)cur[kc][i];
          Ah.u[i] = (unsigned short)(dd >> 16);
          Al.u[i] = (unsigned short)(dd & 0xffffu);
        }
#pragma unroll
        for (int g3 = 0; g3 < 3; g3++) {
          acc[g3] = __builtin_amdgcn_mfma_f32_16x16x32_bf16(Ah.b, wh[g3][kc], acc[g3], 0, 0, 0);
          acc[g3] = __builtin_amdgcn_mfma_f32_16x16x32_bf16(Al.b, wh[g3][kc], acc[g3], 0, 0, 0);
          acc[g3] = __builtin_amdgcn_mfma_f32_16x16x32_bf16(Ah.b, wl[g3][kc], acc[g3], 0, 0, 0);
        }
      }
    }

    // C layout: reg r at (lr,lq) holds D[row=lq*4+r=batch][col=lr]
#pragma unroll
    for (int g3 = 0; g3 < 3; g3++)
#pragma unroll
      for (int r = 0; r < 4; r++)
        part[m][q][g3][lr][lq * 4 + r] = acc[g3][r];
    __syncthreads();

    // ---- gates: 256 threads, one (batch gb, col gj) each (coalesced wire store)
    if (tid < 256) {
      const int col = nb * GC + gj;
      float ir = 0.f, iz = 0.f, inn = 0.f, hr = 0.f, hz = 0.f, hnn = 0.f;
#pragma unroll
      for (int qq = 0; qq < 4; qq++) {
        ir  += part[0][qq][0][gj][gb];
        iz  += part[0][qq][1][gj][gb];
        inn += part[0][qq][2][gj][gb];
        hr  += part[1][qq][0][gj][gb];
        hz  += part[1][qq][1][gj][gb];
        hnn += part[1][qq][2][gj][gb];
      }
      float rr = 1.f / (1.f + expf(-(ir + bi_s[0][gj] + hr + bh_s[0][gj])));
      float zz = 1.f / (1.f + expf(-(iz + bi_s[1][gj] + hz + bh_s[1][gj])));
      float nn = tanhf(inn + bi_s[2][gj] + rr * (hnn + bh_s[2][gj]));
      float hv = (1.f - zz) * nn + zz * hloc[gb][gj];
      hloc[gb][gj] = hv;
      unsigned short h16 = f2bf(hv);
      unsigned short l16 = f2bf(hv - bf2f(h16));
      // tagged store: data + readiness in one atomic 8B word, fire-and-forget
      u64* wr = hb + (size_t)((s + 1) & 1) * NSLOT;
      u64 wv = ((u64)(unsigned)(s + 1) << 32) |
               (u64)(((unsigned)h16 << 16) | (unsigned)l16);
      __hip_atomic_store(wr + gw, wv, __ATOMIC_RELAXED, __HIP_MEMORY_SCOPE_AGENT);
      if (s >= CTXN && s < T_SEQ - CTXN) {
        float xv = x[((size_t)(b0 + gb) * T_SEQ + t) * HDIM + col];   // L1/L2-hot
        out[((size_t)(b0 + gb) * OUT_T + (s - CTXN)) * 1024 + d * HDIM + col] = hv + xv;
      }
    }
    __syncthreads();   // protect part[] / hloc for next step
  }
}

extern "C" void kernel_launch(void* const* d_in, const int* in_sizes, int n_in,
                              void* d_out, int out_size, void* d_ws, size_t ws_size,
                              hipStream_t stream) {
  (void)in_sizes; (void)n_in; (void)out_size; (void)ws_size;
  const float* v_in  = (const float*)d_in[0];
  const float* Wih_f = (const float*)d_in[1];
  const float* Whh_f = (const float*)d_in[2];
  const float* bih_f = (const float*)d_in[3];
  const float* bhh_f = (const float*)d_in[4];
  const float* Wih_b = (const float*)d_in[5];
  const float* Whh_b = (const float*)d_in[6];
  const float* bih_b = (const float*)d_in[7];
  const float* bhh_b = (const float*)d_in[8];
  float* out = (float*)d_out;
  char* ws = (char*)d_ws;

  // ws layout (~13 MB total):
  //   [0, 1M)         hbuf : 8 groups x 2 slots x 8192 tagged u64 (wire layout)
  //   [1M,  +3M)      wih_hi [2][1536][512] bf16
  //   [4M,  +3M)      wih_lo
  //   [7M,  +3M)      whh_hi
  //   [10M, +3M)      whh_lo
  u64* hbuf = (u64*)ws;
  unsigned short* wih_hi = (unsigned short*)(ws + (size_t)(1 << 20));
  unsigned short* wih_lo = (unsigned short*)(ws + (size_t)(4 << 20));
  unsigned short* whh_hi = (unsigned short*)(ws + (size_t)(7 << 20));
  unsigned short* whh_lo = (unsigned short*)(ws + (size_t)(10 << 20));

  // zero hbuf: slot0 tag=0 data=0 == valid h(0)=0; slot1 tag 0 != 1 -> polled
  hipMemsetAsync(ws, 0, (size_t)8 * 2 * NSLOT * 8, stream);
  split_w<<<dim3(768, 4), 256, 0, stream>>>(Wih_f, Wih_b, Whh_f, Whh_b,
                                            wih_hi, wih_lo, whh_hi, whh_lo);
  gru_rec<<<256, 512, 0, stream>>>(v_in, wih_hi, wih_lo, whh_hi, whh_lo,
                                   bih_f, bhh_f, bih_b, bhh_b, out, hbuf);
}